// Round 2
// baseline (466.685 us; speedup 1.0000x reference)
//
#include <hip/hip_runtime.h>
#include <math.h>

// Problem constants (fixed): B=4, C=256, H=64, W=128, D=4, 81 shifts, C/R=16
// out: [B, 81, H, W] fp32 (2,654,208 elements)
// ws: pooled [4*81*256] f32 + At [4*256*81] f32 = 663,552 bytes

#define HH 64
#define WW 128
#define CC 256
#define BB 4

// ---------------------------------------------------------------------------
// Kernel A: pooled[b, s, c] = sum_{h,w} f1[b,c,h,w] * f2pad[b,c,h+i,w+j]
// (raw sum; /8192 applied in kernel B). One block per (b,c) plane.
// LDS: padded f2 plane 72 rows x 35 float4 chunks (40.3 KB) + 32x81 row-pair
// partials (10.4 KB) = 50.7 KB -> 3 blocks/CU (was 61 KB -> 2 blocks/CU).
// ---------------------------------------------------------------------------
__global__ __launch_bounds__(256, 3) void corr_pool_kernel(
    const float* __restrict__ f1, const float* __restrict__ f2,
    float* __restrict__ pooled) {
  const int t  = threadIdx.x;
  const int bc = blockIdx.x;                    // b*256 + c
  const float* f1p = f1 + (size_t)bc * (HH * WW);
  const float* f2p = f2 + (size_t)bc * (HH * WW);

  __shared__ float4 f2s4[72 * 35];              // 40,320 B padded f2 plane
  __shared__ float  rowpart[32 * 81];           // 10,368 B row-pair partials

  const float4 z4 = make_float4(0.f, 0.f, 0.f, 0.f);
  for (int u = t; u < 72 * 35; u += 256) f2s4[u] = z4;
  __syncthreads();
  for (int u = t; u < 2048; u += 256) {         // 64 rows x 32 chunks interior
    const int r = u >> 5, k = u & 31;
    const float4 v = *(const float4*)(f2p + (r << 7) + (k << 2));
    f2s4[(r + 4) * 35 + 1 + k] = v;
  }
  __syncthreads();

  const int h   = t >> 2;                       // 0..63
  const int seg = t & 3;
  const int w0  = seg << 5;                     // 0,32,64,96

  alignas(16) float f1r[32];
#pragma unroll
  for (int u = 0; u < 8; ++u)
    *(float4*)&f1r[4 * u] = *(const float4*)(f1p + (h << 7) + w0 + (u << 2));

  for (int i = 0; i < 9; ++i) {
    alignas(16) float f2r[40];
    const float4* src = &f2s4[(h + i) * 35 + (w0 >> 2)];
#pragma unroll
    for (int m = 0; m < 10; ++m) *(float4*)&f2r[4 * m] = src[m];

    float s9[9];
#pragma unroll
    for (int j = 0; j < 9; ++j) s9[j] = 0.f;
#pragma unroll
    for (int k = 0; k < 32; ++k) {
      const float a = f1r[k];
#pragma unroll
      for (int j = 0; j < 9; ++j) s9[j] += a * f2r[k + j];
    }
    // reduce over lane bits 0..2: 4 w-segs x 2 adjacent rows
#pragma unroll
    for (int j = 0; j < 9; ++j) {
      s9[j] += __shfl_xor(s9[j], 1);
      s9[j] += __shfl_xor(s9[j], 2);
      s9[j] += __shfl_xor(s9[j], 4);
    }
    if ((t & 7) == 0) {
      const int hp = t >> 3;                    // row-pair 0..31
#pragma unroll
      for (int j = 0; j < 9; ++j) rowpart[hp * 81 + i * 9 + j] = s9[j];
    }
  }
  __syncthreads();

  if (t < 81) {
    float acc = 0.f;
    for (int hp = 0; hp < 32; ++hp) acc += rowpart[hp * 81 + t];
    const int b = bc >> 8, c = bc & 255;
    pooled[(size_t)(b * 81 + t) * 256 + c] = acc;   // raw sum
  }
}

// ---------------------------------------------------------------------------
// Kernel B: At[b, c, s] = sigmoid(W2 (W1 (pooled/8192) + b1) + b2)
// Transposed output layout for kernel C's per-channel coefficient reads.
// One block per (b,s) pair.
// ---------------------------------------------------------------------------
__global__ __launch_bounds__(256) void mlp_kernel(
    const float* __restrict__ pooled, const float* __restrict__ w1,
    const float* __restrict__ b1, const float* __restrict__ w2,
    const float* __restrict__ b2, float* __restrict__ At) {
  const int bs = blockIdx.x;                    // b*81 + s
  const int t  = threadIdx.x;
  const int b  = bs / 81;
  const int s  = bs - b * 81;
  __shared__ float p[256];
  __shared__ float hid[16];

  p[t] = pooled[(size_t)bs * 256 + t] * (1.0f / 8192.0f);
  __syncthreads();

  const int g = t >> 4, ln = t & 15;
  float acc = 0.f;
#pragma unroll
  for (int m = 0; m < 16; ++m) {
    const int c = (m << 4) + ln;
    acc += w1[(g << 8) + c] * p[c];
  }
  acc += __shfl_xor(acc, 1);
  acc += __shfl_xor(acc, 2);
  acc += __shfl_xor(acc, 4);
  acc += __shfl_xor(acc, 8);
  if (ln == 0) hid[g] = acc + b1[g];
  __syncthreads();

  float acc2 = b2[t];
#pragma unroll
  for (int k = 0; k < 16; ++k) acc2 += w2[(t << 4) + k] * hid[k];
  const float sv = 1.0f / (1.0f + __expf(-acc2));
  At[((size_t)(b * 256 + t)) * 81 + s] = sv;    // transposed: [b][c][81]
}

// ---------------------------------------------------------------------------
// Kernel C: out[b, i*9+j, h, w] += (1/256) sum_{c in half} At[b,c,i*9+j] *
//                                   f1[c,h,w] * f2[c,h+i-4,w+j-4]
// grid = 576: 64 tiles (b x 8-row-tile x channel-half) x 9 i-shifts,
// XCD-swizzled so a tile's 9 i-blocks share one XCD's L2.
// block = 256 thr = 8 rows x 32 float4-cols; 8 channels staged per barrier
// (32 barriers vs 256 before); f1 preloaded 8-deep into registers;
// coefficients staged once into LDS. Halves combined via atomicAdd
// into memset-zeroed out.
// ---------------------------------------------------------------------------
#define SCH 8
__global__ __launch_bounds__(256, 4) void out_kernel(
    const float* __restrict__ f1, const float* __restrict__ f2,
    const float* __restrict__ At, float* __restrict__ out) {
  // XCD swizzle decode: bid = x + 8*(i + 9*tq), tile = 8*tq + x
  const int bid  = blockIdx.x;
  const int x    = bid & 7;
  const int q    = bid >> 3;                    // 0..71
  const int i    = q % 9;
  const int tq   = q / 9;                       // 0..7
  const int tile = tq * 8 + x;                  // 0..63
  const int half = tile & 1;
  const int rt   = (tile >> 1) & 7;
  const int b    = tile >> 4;
  const int h0   = rt << 3;
  const int c0b  = half << 7;                   // channel-half base

  const int t    = threadIdx.x;
  const int r    = t >> 5;                      // 0..7
  const int cidx = t & 31;
  const int w0   = cidx << 2;
  const int h    = h0 + r;

  __shared__ float4 f2s[SCH * 8 * 35];          // 35,840 B (row stride 35)
  __shared__ float  aLds[128 * 9];              // 4,608 B coefficients

  const float* f1b = f1 + (size_t)b * CC * (HH * WW);
  const float* f2b = f2 + (size_t)b * CC * (HH * WW);

  // stage this block's 128x9 coefficient slab once
  for (int u = t; u < 128 * 9; u += 256) {
    const int cl = u / 9, j = u - cl * 9;
    aLds[u] = At[((size_t)(b * 256 + c0b + cl)) * 81 + i * 9 + j];
  }

  float acc[9][4];
#pragma unroll
  for (int j = 0; j < 9; ++j)
#pragma unroll
    for (int k = 0; k < 4; ++k) acc[j][k] = 0.f;

  const float4 z4 = make_float4(0.f, 0.f, 0.f, 0.f);

  for (int c0 = 0; c0 < 128; c0 += SCH) {
    // stage 8 channels x 8 shifted rows (with w-halo) into LDS
    for (int u = t; u < SCH * 8 * 34; u += 256) {
      const int cc  = u / 272;
      const int rem = u - cc * 272;
      const int rr  = rem / 34;
      const int kk  = rem - rr * 34;            // padded chunk col 0..33
      const int hr  = h0 + rr + i - 4;
      float4 v = z4;
      if ((unsigned)hr < 64u && kk >= 1 && kk <= 32)
        v = *(const float4*)(f2b + (size_t)(c0b + c0 + cc) * 8192 + (hr << 7) +
                             ((kk - 1) << 2));
      f2s[(cc * 8 + rr) * 35 + kk] = v;
    }

    // preload f1 for all 8 channels (overlaps barrier wait)
    float4 xv[SCH];
#pragma unroll
    for (int cc = 0; cc < SCH; ++cc)
      xv[cc] = *(const float4*)(f1b + (size_t)(c0b + c0 + cc) * 8192 +
                                (h << 7) + w0);

    __syncthreads();                            // staging complete

#pragma unroll
    for (int cc = 0; cc < SCH; ++cc) {
      alignas(16) float f2r[12];
      const float4* srcp = &f2s[(cc * 8 + r) * 35 + cidx];
      *(float4*)&f2r[0] = srcp[0];
      *(float4*)&f2r[4] = srcp[1];
      *(float4*)&f2r[8] = srcp[2];

      alignas(16) float xx[4] = {xv[cc].x, xv[cc].y, xv[cc].z, xv[cc].w};

#pragma unroll
      for (int j = 0; j < 9; ++j) {
        const float wj = aLds[(c0 + cc) * 9 + j];
#pragma unroll
        for (int k = 0; k < 4; ++k) acc[j][k] += wj * (xx[k] * f2r[k + j]);
      }
    }
    __syncthreads();                            // before next stage overwrites
  }

  const float inv = 1.0f / 256.0f;
#pragma unroll
  for (int j = 0; j < 9; ++j) {
    float* op = out + (((size_t)(b * 81 + i * 9 + j) * 64 + h) << 7) + w0;
#pragma unroll
    for (int k = 0; k < 4; ++k) atomicAdd(op + k, acc[j][k] * inv);
  }
}

// ---------------------------------------------------------------------------
extern "C" void kernel_launch(void* const* d_in, const int* in_sizes, int n_in,
                              void* d_out, int out_size, void* d_ws, size_t ws_size,
                              hipStream_t stream) {
  const float* feat1 = (const float*)d_in[0];
  const float* feat2 = (const float*)d_in[1];
  const float* w1    = (const float*)d_in[2];
  const float* b1    = (const float*)d_in[3];
  const float* w2    = (const float*)d_in[4];
  const float* b2    = (const float*)d_in[5];
  float* out = (float*)d_out;

  float* pooled = (float*)d_ws;                 // 4*81*256 floats
  float* At     = pooled + 4 * 81 * 256;        // 4*256*81 floats (transposed)

  hipMemsetAsync(out, 0, (size_t)out_size * sizeof(float), stream);
  corr_pool_kernel<<<1024, 256, 0, stream>>>(feat1, feat2, pooled);
  mlp_kernel<<<4 * 81, 256, 0, stream>>>(pooled, w1, b1, w2, b2, At);
  out_kernel<<<576, 256, 0, stream>>>(feat1, feat2, At, out);
}

// Round 3
// 281.480 us; speedup vs baseline: 1.6580x; 1.6580x over previous
//
#include <hip/hip_runtime.h>
#include <math.h>

// Problem constants (fixed): B=4, C=256, H=64, W=128, D=4, 81 shifts, C/R=16
// out: [B, 81, H, W] fp32 (2,654,208 elements)
// ws: pooled [4*81*256] f32 + At [4*256*81] f32 = 663,552 bytes

#define HH 64
#define WW 128
#define CC 256
#define BB 4

// ---------------------------------------------------------------------------
// Kernel A: pooled[b, s, c] = sum_{h,w} f1[b,c,h,w] * f2pad[b,c,h+i,w+j]
// (raw sum; /8192 applied in kernel B). One block per (b,c) plane.
// LDS: padded f2 plane 72 rows x 35 float4 chunks (40.3 KB) + 32x81 row-pair
// partials (10.4 KB) = 50.7 KB -> 3 blocks/CU.
// ---------------------------------------------------------------------------
__global__ __launch_bounds__(256, 3) void corr_pool_kernel(
    const float* __restrict__ f1, const float* __restrict__ f2,
    float* __restrict__ pooled) {
  const int t  = threadIdx.x;
  const int bc = blockIdx.x;                    // b*256 + c
  const float* f1p = f1 + (size_t)bc * (HH * WW);
  const float* f2p = f2 + (size_t)bc * (HH * WW);

  __shared__ float4 f2s4[72 * 35];              // 40,320 B padded f2 plane
  __shared__ float  rowpart[32 * 81];           // 10,368 B row-pair partials

  const float4 z4 = make_float4(0.f, 0.f, 0.f, 0.f);
  for (int u = t; u < 72 * 35; u += 256) f2s4[u] = z4;
  __syncthreads();
  for (int u = t; u < 2048; u += 256) {         // 64 rows x 32 chunks interior
    const int r = u >> 5, k = u & 31;
    const float4 v = *(const float4*)(f2p + (r << 7) + (k << 2));
    f2s4[(r + 4) * 35 + 1 + k] = v;
  }
  __syncthreads();

  const int h   = t >> 2;                       // 0..63
  const int seg = t & 3;
  const int w0  = seg << 5;                     // 0,32,64,96

  alignas(16) float f1r[32];
#pragma unroll
  for (int u = 0; u < 8; ++u)
    *(float4*)&f1r[4 * u] = *(const float4*)(f1p + (h << 7) + w0 + (u << 2));

  for (int i = 0; i < 9; ++i) {
    alignas(16) float f2r[40];
    const float4* src = &f2s4[(h + i) * 35 + (w0 >> 2)];
#pragma unroll
    for (int m = 0; m < 10; ++m) *(float4*)&f2r[4 * m] = src[m];

    float s9[9];
#pragma unroll
    for (int j = 0; j < 9; ++j) s9[j] = 0.f;
#pragma unroll
    for (int k = 0; k < 32; ++k) {
      const float a = f1r[k];
#pragma unroll
      for (int j = 0; j < 9; ++j) s9[j] += a * f2r[k + j];
    }
    // reduce over lane bits 0..2: 4 w-segs x 2 adjacent rows
#pragma unroll
    for (int j = 0; j < 9; ++j) {
      s9[j] += __shfl_xor(s9[j], 1);
      s9[j] += __shfl_xor(s9[j], 2);
      s9[j] += __shfl_xor(s9[j], 4);
    }
    if ((t & 7) == 0) {
      const int hp = t >> 3;                    // row-pair 0..31
#pragma unroll
      for (int j = 0; j < 9; ++j) rowpart[hp * 81 + i * 9 + j] = s9[j];
    }
  }
  __syncthreads();

  if (t < 81) {
    float acc = 0.f;
    for (int hp = 0; hp < 32; ++hp) acc += rowpart[hp * 81 + t];
    const int b = bc >> 8, c = bc & 255;
    pooled[(size_t)(b * 81 + t) * 256 + c] = acc;   // raw sum
  }
}

// ---------------------------------------------------------------------------
// Kernel B: At[b, c, s] = sigmoid(W2 (W1 (pooled/8192) + b1) + b2)
// Transposed output layout for kernel C's wave-uniform coefficient s_loads.
// ---------------------------------------------------------------------------
__global__ __launch_bounds__(256) void mlp_kernel(
    const float* __restrict__ pooled, const float* __restrict__ w1,
    const float* __restrict__ b1, const float* __restrict__ w2,
    const float* __restrict__ b2, float* __restrict__ At) {
  const int bs = blockIdx.x;                    // b*81 + s
  const int t  = threadIdx.x;
  const int b  = bs / 81;
  const int s  = bs - b * 81;
  __shared__ float p[256];
  __shared__ float hid[16];

  p[t] = pooled[(size_t)bs * 256 + t] * (1.0f / 8192.0f);
  __syncthreads();

  const int g = t >> 4, ln = t & 15;
  float acc = 0.f;
#pragma unroll
  for (int m = 0; m < 16; ++m) {
    const int c = (m << 4) + ln;
    acc += w1[(g << 8) + c] * p[c];
  }
  acc += __shfl_xor(acc, 1);
  acc += __shfl_xor(acc, 2);
  acc += __shfl_xor(acc, 4);
  acc += __shfl_xor(acc, 8);
  if (ln == 0) hid[g] = acc + b1[g];
  __syncthreads();

  float acc2 = b2[t];
#pragma unroll
  for (int k = 0; k < 16; ++k) acc2 += w2[(t << 4) + k] * hid[k];
  const float sv = 1.0f / (1.0f + __expf(-acc2));
  At[((size_t)(b * 256 + t)) * 81 + s] = sv;    // transposed: [b][c][81]
}

// ---------------------------------------------------------------------------
// Kernel C: out[b, i*9+j, h, w] = (1/256) sum_c At[b,c,i*9+j] *
//                                  f1[b,c,h,w] * f2[b,c,h+i-4,w+j-4]
// 1152 single-wave blocks = 4b x 9i x 32 two-row tiles, XCD-swizzled so the
// 9 i-blocks of one tile share an XCD's L2. No LDS, no barriers, no atomics:
// per channel 4 global float4 loads (L1-resident overlap) + 72 FMA; the 9
// coefficients are wave-uniform -> s_load. Every output written exactly once.
// ---------------------------------------------------------------------------
__global__ __launch_bounds__(64, 4) void out_kernel(
    const float* __restrict__ f1, const float* __restrict__ f2,
    const float* __restrict__ At, float* __restrict__ out) {
  // bid = x + 8*(i + 9*tq); tile = tq*8 + x keeps i-siblings on one XCD
  const int bid  = blockIdx.x;
  const int x    = bid & 7;
  const int q    = bid >> 3;                    // 0..143
  const int i    = q % 9;
  const int tq   = q / 9;                       // 0..15
  const int tile = tq * 8 + x;                  // 0..127
  const int b    = tile >> 5;
  const int rt   = tile & 31;
  const int h0   = rt << 1;

  const int t    = threadIdx.x;
  const int r    = t >> 5;                      // 0..1
  const int cidx = t & 31;
  const int w0   = cidx << 2;
  const int h    = h0 + r;
  const int hr   = h + i - 4;
  const bool rowok = ((unsigned)hr < 64u);

  float acc[9][4];
#pragma unroll
  for (int j = 0; j < 9; ++j)
#pragma unroll
    for (int k = 0; k < 4; ++k) acc[j][k] = 0.f;

  if (rowok) {
    const float* p1 = f1 + (size_t)b * (CC * 8192) + (h << 7) + w0;
    const float* p2 = f2 + (size_t)b * (CC * 8192) + (hr << 7);
    const float* Ab = At + (size_t)b * (CC * 81) + i * 9;

    // w-edge handling: clamp addresses in-bounds, select 0 after load
    const bool vA  = (cidx > 0);
    const bool vC  = (cidx < 31);
    const int ofsA = vA ? (w0 - 4) : 0;
    const int ofsC = vC ? (w0 + 4) : 120;

#pragma unroll 2
    for (int c = 0; c < 256; ++c) {
      const float4 xv = *(const float4*)(p1);
      const float4 fA = *(const float4*)(p2 + ofsA);
      const float4 fB = *(const float4*)(p2 + w0);
      const float4 fC = *(const float4*)(p2 + ofsC);

      alignas(16) float f2r[12];
      f2r[0] = vA ? fA.x : 0.f;
      f2r[1] = vA ? fA.y : 0.f;
      f2r[2] = vA ? fA.z : 0.f;
      f2r[3] = vA ? fA.w : 0.f;
      f2r[4] = fB.x; f2r[5] = fB.y; f2r[6] = fB.z; f2r[7] = fB.w;
      f2r[8]  = vC ? fC.x : 0.f;
      f2r[9]  = vC ? fC.y : 0.f;
      f2r[10] = vC ? fC.z : 0.f;
      f2r[11] = vC ? fC.w : 0.f;

      alignas(16) const float xx[4] = {xv.x, xv.y, xv.z, xv.w};

      const float* avp = Ab + (size_t)c * 81;   // wave-uniform -> s_load
#pragma unroll
      for (int j = 0; j < 9; ++j) {
        const float wj = avp[j];
#pragma unroll
        for (int k = 0; k < 4; ++k) acc[j][k] += wj * (xx[k] * f2r[k + j]);
      }
      p1 += 8192;
      p2 += 8192;
    }
  }

  const float inv = 1.0f / 256.0f;
#pragma unroll
  for (int j = 0; j < 9; ++j) {
    float4 o;
    o.x = acc[j][0] * inv;
    o.y = acc[j][1] * inv;
    o.z = acc[j][2] * inv;
    o.w = acc[j][3] * inv;
    *(float4*)(out + (((size_t)(b * 81 + i * 9 + j) * 64 + h) << 7) + w0) = o;
  }
}

// ---------------------------------------------------------------------------
extern "C" void kernel_launch(void* const* d_in, const int* in_sizes, int n_in,
                              void* d_out, int out_size, void* d_ws, size_t ws_size,
                              hipStream_t stream) {
  const float* feat1 = (const float*)d_in[0];
  const float* feat2 = (const float*)d_in[1];
  const float* w1    = (const float*)d_in[2];
  const float* b1    = (const float*)d_in[3];
  const float* w2    = (const float*)d_in[4];
  const float* b2    = (const float*)d_in[5];
  float* out = (float*)d_out;

  float* pooled = (float*)d_ws;                 // 4*81*256 floats
  float* At     = pooled + 4 * 81 * 256;        // 4*256*81 floats (transposed)

  corr_pool_kernel<<<1024, 256, 0, stream>>>(feat1, feat2, pooled);
  mlp_kernel<<<4 * 81, 256, 0, stream>>>(pooled, w1, b1, w2, b2, At);
  out_kernel<<<1152, 64, 0, stream>>>(feat1, feat2, At, out);
}

// Round 4
// 217.882 us; speedup vs baseline: 2.1419x; 1.2919x over previous
//
#include <hip/hip_runtime.h>
#include <math.h>

// Problem constants (fixed): B=4, C=256, H=64, W=128, D=4, 81 shifts, C/R=16
// out: [B, 81, H, W] fp32 (2,654,208 elements)
// ws layout (floats):
//   [0)        pooled strip-0 partial  82,944
//   [82944)    pooled strip-1 partial  82,944
//   [165888)   At (transposed coeffs)  82,944
//   [248832)   C channel-half-1 partial 2,654,208
// total ~11.6 MB

#define HH 64
#define WW 128
#define CC 256
#define BB 4

// ---------------------------------------------------------------------------
// Kernel A: partial pooled over a 32-row strip.
// grid = 2048 (1024 bc-planes x 2 strips), 256 threads.
// LDS: f2 strip rows h0-4..h0+35 padded (40 x 35 float4 = 22.4 KB) +
// rowpair partials 16x81 (5.2 KB) = 27.6 KB -> 5 blocks/CU (was 3).
// Single staging barrier; thread = (row hl = t>>3, seg = t&7, 16 cols).
// Strip partials summed inside kernel B.
// ---------------------------------------------------------------------------
__global__ __launch_bounds__(256) void corr_pool_kernel(
    const float* __restrict__ f1, const float* __restrict__ f2,
    float* __restrict__ pooled_part) {
  const int bid   = blockIdx.x;
  const int strip = bid & 1;
  const int bc    = bid >> 1;
  const int h0    = strip << 5;                 // 0 or 32
  const float* f1p = f1 + (size_t)bc * (HH * WW);
  const float* f2p = f2 + (size_t)bc * (HH * WW);

  __shared__ float4 f2s[40 * 35];               // 22,400 B
  __shared__ float  rowpart[16 * 81];           // 5,184 B

  const int t = threadIdx.x;
  const float4 z4 = make_float4(0.f, 0.f, 0.f, 0.f);
  for (int u = t; u < 40 * 35; u += 256) {      // zero-halo staging, 1 barrier
    const int rl = u / 35, k = u - rl * 35;     // padded chunk col 0..34
    const int gr = h0 - 4 + rl;
    float4 v = z4;
    if ((unsigned)gr < 64u && k >= 1 && k <= 32)
      v = *(const float4*)(f2p + (gr << 7) + ((k - 1) << 2));
    f2s[u] = v;
  }

  const int hl = t >> 3, seg = t & 7, w0 = seg << 4;
  alignas(16) float f1r[16];
#pragma unroll
  for (int m = 0; m < 4; ++m)
    *(float4*)&f1r[4 * m] =
        *(const float4*)(f1p + ((h0 + hl) << 7) + w0 + (m << 2));
  __syncthreads();

  for (int i = 0; i < 9; ++i) {
    alignas(16) float f2r[24];                  // cols w0-4 .. w0+19
    const float4* src = &f2s[(hl + i) * 35 + (seg << 2)];
#pragma unroll
    for (int m = 0; m < 6; ++m) *(float4*)&f2r[4 * m] = src[m];

    float s9[9];
#pragma unroll
    for (int j = 0; j < 9; ++j) s9[j] = 0.f;
#pragma unroll
    for (int k = 0; k < 16; ++k) {
      const float a = f1r[k];
#pragma unroll
      for (int j = 0; j < 9; ++j) s9[j] += a * f2r[k + j];
    }
    // reduce over 8 segs (lane bits 0..2) and row-pair (lane bit 3)
#pragma unroll
    for (int j = 0; j < 9; ++j) {
      s9[j] += __shfl_xor(s9[j], 1);
      s9[j] += __shfl_xor(s9[j], 2);
      s9[j] += __shfl_xor(s9[j], 4);
      s9[j] += __shfl_xor(s9[j], 8);
    }
    if ((t & 15) == 0) {
      const int pr = t >> 4;                    // row-pair 0..15
#pragma unroll
      for (int j = 0; j < 9; ++j) rowpart[pr * 81 + i * 9 + j] = s9[j];
    }
  }
  __syncthreads();

  if (t < 81) {
    float acc = 0.f;
#pragma unroll
    for (int p = 0; p < 16; ++p) acc += rowpart[p * 81 + t];
    const int b = bc >> 8, c = bc & 255;
    pooled_part[(size_t)strip * 82944 + (size_t)(b * 81 + t) * 256 + c] = acc;
  }
}

// ---------------------------------------------------------------------------
// Kernel B: At[b, c, s] = sigmoid(MLP(mean pooled)). Sums the two strip
// partials while loading. Transposed output for kernel C's uniform s_loads.
// ---------------------------------------------------------------------------
__global__ __launch_bounds__(256) void mlp_kernel(
    const float* __restrict__ pooled_part, const float* __restrict__ w1,
    const float* __restrict__ b1, const float* __restrict__ w2,
    const float* __restrict__ b2, float* __restrict__ At) {
  const int bs = blockIdx.x;                    // b*81 + s
  const int t  = threadIdx.x;
  const int b  = bs / 81;
  const int s  = bs - b * 81;
  __shared__ float p[256];
  __shared__ float hid[16];

  p[t] = (pooled_part[(size_t)bs * 256 + t] +
          pooled_part[82944 + (size_t)bs * 256 + t]) * (1.0f / 8192.0f);
  __syncthreads();

  const int g = t >> 4, ln = t & 15;
  float acc = 0.f;
#pragma unroll
  for (int m = 0; m < 16; ++m) {
    const int c = (m << 4) + ln;
    acc += w1[(g << 8) + c] * p[c];
  }
  acc += __shfl_xor(acc, 1);
  acc += __shfl_xor(acc, 2);
  acc += __shfl_xor(acc, 4);
  acc += __shfl_xor(acc, 8);
  if (ln == 0) hid[g] = acc + b1[g];
  __syncthreads();

  float acc2 = b2[t];
#pragma unroll
  for (int k = 0; k < 16; ++k) acc2 += w2[(t << 4) + k] * hid[k];
  const float sv = 1.0f / (1.0f + __expf(-acc2));
  At[((size_t)(b * 256 + t)) * 81 + s] = sv;    // transposed: [b][c][81]
}

// ---------------------------------------------------------------------------
// Kernel C: channel-half partial of
//   out[b, i*9+j, h, w] = (1/256) sum_c At[b,c,i*9+j]*f1[c,h,w]*f2[c,h+i-4,w+j-4]
// grid = 2304 single-wave blocks = 4b x 9i x 32 two-row tiles x 2 channel
// halves, XCD-swizzled. Depth-1 software prefetch of the next channel's 4
// float4 loads. Half-0 writes out, half-1 writes ws partial (combined after).
// ---------------------------------------------------------------------------
__global__ __launch_bounds__(64, 4) void out_kernel(
    const float* __restrict__ f1, const float* __restrict__ f2,
    const float* __restrict__ At, float* __restrict__ out,
    float* __restrict__ part) {
  // bid = x + 8*(i + 9*tq); tile = tq*8 + x keeps i-siblings on one XCD
  const int bid  = blockIdx.x;
  const int x    = bid & 7;
  const int q    = bid >> 3;                    // 0..287
  const int i    = q % 9;
  const int tq   = q / 9;                       // 0..31
  const int tile = tq * 8 + x;                  // 0..255
  const int half = tile & 1;
  const int rt   = (tile >> 1) & 31;
  const int b    = tile >> 6;
  const int h0   = rt << 1;

  const int t    = threadIdx.x;
  const int r    = t >> 5;                      // 0..1
  const int cidx = t & 31;
  const int w0   = cidx << 2;
  const int h    = h0 + r;
  const int hr   = h + i - 4;
  const bool rowok = ((unsigned)hr < 64u);

  float acc[9][4];
#pragma unroll
  for (int j = 0; j < 9; ++j)
#pragma unroll
    for (int k = 0; k < 4; ++k) acc[j][k] = 0.f;

  if (rowok) {
    const int c0 = half << 7;
    const float* p1 = f1 + (size_t)b * (CC * 8192) + (size_t)c0 * 8192 +
                      (h << 7) + w0;
    const float* p2 = f2 + (size_t)b * (CC * 8192) + (size_t)c0 * 8192 +
                      (hr << 7);
    const float* Ab = At + (size_t)b * (CC * 81) + (size_t)c0 * 81 + i * 9;

    const bool vA  = (cidx > 0);
    const bool vC  = (cidx < 31);
    const int ofsA = vA ? (w0 - 4) : 0;
    const int ofsC = vC ? (w0 + 4) : 120;

    // depth-1 prefetch pipeline
    float4 nx = *(const float4*)(p1);
    float4 nA = *(const float4*)(p2 + ofsA);
    float4 nB = *(const float4*)(p2 + w0);
    float4 nC = *(const float4*)(p2 + ofsC);

#pragma unroll 4
    for (int c = 0; c < 128; ++c) {
      const float4 xv = nx, fA = nA, fB = nB, fC = nC;
      if (c + 1 < 128) {
        p1 += 8192;
        p2 += 8192;
        nx = *(const float4*)(p1);
        nA = *(const float4*)(p2 + ofsA);
        nB = *(const float4*)(p2 + w0);
        nC = *(const float4*)(p2 + ofsC);
      }

      alignas(16) float f2r[12];
      f2r[0] = vA ? fA.x : 0.f;
      f2r[1] = vA ? fA.y : 0.f;
      f2r[2] = vA ? fA.z : 0.f;
      f2r[3] = vA ? fA.w : 0.f;
      f2r[4] = fB.x; f2r[5] = fB.y; f2r[6] = fB.z; f2r[7] = fB.w;
      f2r[8]  = vC ? fC.x : 0.f;
      f2r[9]  = vC ? fC.y : 0.f;
      f2r[10] = vC ? fC.z : 0.f;
      f2r[11] = vC ? fC.w : 0.f;

      alignas(16) const float xx[4] = {xv.x, xv.y, xv.z, xv.w};

      const float* avp = Ab + (size_t)c * 81;   // wave-uniform -> s_load
#pragma unroll
      for (int j = 0; j < 9; ++j) {
        const float wj = avp[j];
#pragma unroll
        for (int k = 0; k < 4; ++k) acc[j][k] += wj * (xx[k] * f2r[k + j]);
      }
    }
  }

  float* dst = half ? part : out;
  const float inv = 1.0f / 256.0f;
#pragma unroll
  for (int j = 0; j < 9; ++j) {
    float4 o;
    o.x = acc[j][0] * inv;
    o.y = acc[j][1] * inv;
    o.z = acc[j][2] * inv;
    o.w = acc[j][3] * inv;
    *(float4*)(dst + (((size_t)(b * 81 + i * 9 + j) * 64 + h) << 7) + w0) = o;
  }
}

// ---------------------------------------------------------------------------
// Combine: out += channel-half-1 partial. 663,552 float4s, grid 2592 x 256.
// ---------------------------------------------------------------------------
__global__ __launch_bounds__(256) void combine_kernel(
    float* __restrict__ out, const float* __restrict__ part) {
  const size_t idx = (size_t)blockIdx.x * 256 + threadIdx.x;  // float4 index
  float4* o4       = (float4*)out;
  const float4* p4 = (const float4*)part;
  const float4 a = o4[idx], p = p4[idx];
  float4 rv;
  rv.x = a.x + p.x; rv.y = a.y + p.y; rv.z = a.z + p.z; rv.w = a.w + p.w;
  o4[idx] = rv;
}

// ---------------------------------------------------------------------------
extern "C" void kernel_launch(void* const* d_in, const int* in_sizes, int n_in,
                              void* d_out, int out_size, void* d_ws, size_t ws_size,
                              hipStream_t stream) {
  const float* feat1 = (const float*)d_in[0];
  const float* feat2 = (const float*)d_in[1];
  const float* w1    = (const float*)d_in[2];
  const float* b1    = (const float*)d_in[3];
  const float* w2    = (const float*)d_in[4];
  const float* b2    = (const float*)d_in[5];
  float* out = (float*)d_out;

  float* pooled_part = (float*)d_ws;            // 2 x 82,944 floats
  float* At          = pooled_part + 2 * 82944; // 82,944 floats
  float* cpart       = At + 82944;              // 2,654,208 floats

  corr_pool_kernel<<<2048, 256, 0, stream>>>(feat1, feat2, pooled_part);
  mlp_kernel<<<4 * 81, 256, 0, stream>>>(pooled_part, w1, b1, w2, b2, At);
  out_kernel<<<2304, 64, 0, stream>>>(feat1, feat2, At, out, cpart);
  combine_kernel<<<2592, 256, 0, stream>>>(out, cpart);
}

// Round 5
// 195.908 us; speedup vs baseline: 2.3822x; 1.1122x over previous
//
#include <hip/hip_runtime.h>
#include <math.h>

// Problem constants (fixed): B=4, C=256, H=64, W=128, D=4, 81 shifts, C/R=16
// out: [B, 81, H, W] fp32 (2,654,208 elements)
// ws layout (floats):
//   [0)       pooled  82,944
//   [82944)   At      82,944
//   [165888)  C channel-half-1 partial 2,654,208

#define HH 64
#define WW 128
#define CC 256
#define BB 4

// ---------------------------------------------------------------------------
// Kernel A: pooled[b, s, c] = sum_{h,w} f1[b,c,h,w] * f2pad[b,c,h+i,w+j]
// One 576-thread block (9 waves) per (b,c) plane. Thread = (row h = t/9,
// shift-row di = t%9): owns the FULL row -> w-reduction is thread-private,
// NO per-i shuffles (the old 324 ds_swizzle/thread were the LDS-pipe killer).
// LDS: padded f2 plane 72 x 35 float4 (40.3 KB, stride 140 dwords), reused
// after stage 1 as the 64x81 transpose buffer. 3 blocks/CU = 27 waves/CU.
// ---------------------------------------------------------------------------
__global__ __launch_bounds__(576, 6) void corr_pool_kernel(
    const float* __restrict__ f1, const float* __restrict__ f2,
    float* __restrict__ pooled) {
  const int t  = threadIdx.x;
  const int bc = blockIdx.x;                    // b*256 + c
  const float* f1p = f1 + (size_t)bc * (HH * WW);
  const float* f2p = f2 + (size_t)bc * (HH * WW);

  __shared__ float4 f2s4[72 * 35];              // 40,320 B; reused as red buf
  float* red = (float*)f2s4;                    // [64][81] after stage 1

  // --- stage f2 plane with zero halo (single barrier) ---
  const float4 z4 = make_float4(0.f, 0.f, 0.f, 0.f);
  for (int u = t; u < 72 * 35; u += 576) {
    const int rl = u / 35, k = u - rl * 35;     // padded row, padded chunk
    const int gr = rl - 4;                      // f2 row
    float4 v = z4;
    if ((unsigned)gr < 64u && k >= 1 && k <= 32)
      v = *(const float4*)(f2p + (gr << 7) + ((k - 1) << 2));
    f2s4[u] = v;
  }
  __syncthreads();

  // --- stage 1: thread (h, di) accumulates s9[j] over the full row ---
  const int h  = t / 9;                         // 0..63
  const int di = t - h * 9;                     // 0..8
  const float4* f2row = &f2s4[(h + di) * 35];   // padded row h+di
  const float* f1row  = f1p + (h << 7);

  float s9[9];
#pragma unroll
  for (int j = 0; j < 9; ++j) s9[j] = 0.f;

#pragma unroll 2
  for (int seg = 0; seg < 8; ++seg) {
    const int w0 = seg << 4;
    alignas(16) float f1r[16];
#pragma unroll
    for (int m = 0; m < 4; ++m)
      *(float4*)&f1r[4 * m] = *(const float4*)(f1row + w0 + (m << 2));

    alignas(16) float f2w[24];                  // padded cols w0 .. w0+23
#pragma unroll
    for (int m = 0; m < 6; ++m) *(float4*)&f2w[4 * m] = f2row[(seg << 2) + m];

#pragma unroll
    for (int k = 0; k < 16; ++k) {
      const float a = f1r[k];
#pragma unroll
      for (int j = 0; j < 9; ++j) s9[j] += a * f2w[k + j];
    }
  }

  // --- stage 2: transpose through LDS, 81 column sums ---
  __syncthreads();                              // all stage-1 reads done
#pragma unroll
  for (int j = 0; j < 9; ++j) red[h * 81 + di * 9 + j] = s9[j];
  __syncthreads();

  if (t < 81) {
    float acc = 0.f;
#pragma unroll 8
    for (int hh = 0; hh < 64; ++hh) acc += red[hh * 81 + t];
    const int b = bc >> 8, c = bc & 255;
    pooled[(size_t)(b * 81 + t) * 256 + c] = acc;   // raw sum (/8192 in B)
  }
}

// ---------------------------------------------------------------------------
// Kernel B: At[b, c, s] = sigmoid(MLP(pooled/8192)). Transposed output for
// kernel C's wave-uniform coefficient s_loads.
// ---------------------------------------------------------------------------
__global__ __launch_bounds__(256) void mlp_kernel(
    const float* __restrict__ pooled, const float* __restrict__ w1,
    const float* __restrict__ b1, const float* __restrict__ w2,
    const float* __restrict__ b2, float* __restrict__ At) {
  const int bs = blockIdx.x;                    // b*81 + s
  const int t  = threadIdx.x;
  const int b  = bs / 81;
  const int s  = bs - b * 81;
  __shared__ float p[256];
  __shared__ float hid[16];

  p[t] = pooled[(size_t)bs * 256 + t] * (1.0f / 8192.0f);
  __syncthreads();

  const int g = t >> 4, ln = t & 15;
  float acc = 0.f;
#pragma unroll
  for (int m = 0; m < 16; ++m) {
    const int c = (m << 4) + ln;
    acc += w1[(g << 8) + c] * p[c];
  }
  acc += __shfl_xor(acc, 1);
  acc += __shfl_xor(acc, 2);
  acc += __shfl_xor(acc, 4);
  acc += __shfl_xor(acc, 8);
  if (ln == 0) hid[g] = acc + b1[g];
  __syncthreads();

  float acc2 = b2[t];
#pragma unroll
  for (int k = 0; k < 16; ++k) acc2 += w2[(t << 4) + k] * hid[k];
  const float sv = 1.0f / (1.0f + __expf(-acc2));
  At[((size_t)(b * 256 + t)) * 81 + s] = sv;    // transposed: [b][c][81]
}

// ---------------------------------------------------------------------------
// Kernel C: channel-half partial of
//   out[b, i*9+j, h, w] = (1/256) sum_c At[b,c,i*9+j]*f1[c,h,w]*f2[c,h+i-4,w+j-4]
// grid = 2304 single-wave blocks = 4b x 9i x 32 two-row tiles x 2 halves,
// XCD-swizzled. BRANCHLESS depth-1 prefetch (advance clamped via cndmask, no
// control flow in the loop) so the compiler can pipeline with vmcnt(4)
// instead of draining per iteration.
// ---------------------------------------------------------------------------
__global__ __launch_bounds__(64, 4) void out_kernel(
    const float* __restrict__ f1, const float* __restrict__ f2,
    const float* __restrict__ At, float* __restrict__ out,
    float* __restrict__ part) {
  // bid = x + 8*(i + 9*tq); tile = tq*8 + x keeps i-siblings on one XCD
  const int bid  = blockIdx.x;
  const int x    = bid & 7;
  const int q    = bid >> 3;                    // 0..287
  const int i    = q % 9;
  const int tq   = q / 9;                       // 0..31
  const int tile = tq * 8 + x;                  // 0..255
  const int half = tile & 1;
  const int rt   = (tile >> 1) & 31;
  const int b    = tile >> 6;
  const int h0   = rt << 1;

  const int t    = threadIdx.x;
  const int r    = t >> 5;                      // 0..1
  const int cidx = t & 31;
  const int w0   = cidx << 2;
  const int h    = h0 + r;
  const int hr   = h + i - 4;
  const bool rowok = ((unsigned)hr < 64u);

  float acc[9][4];
#pragma unroll
  for (int j = 0; j < 9; ++j)
#pragma unroll
    for (int k = 0; k < 4; ++k) acc[j][k] = 0.f;

  if (rowok) {
    const int c0 = half << 7;
    const float* p1 = f1 + (size_t)b * (CC * 8192) + (size_t)c0 * 8192 +
                      (h << 7) + w0;
    const float* p2 = f2 + (size_t)b * (CC * 8192) + (size_t)c0 * 8192 +
                      (hr << 7);
    const float* Ab = At + (size_t)b * (CC * 81) + (size_t)c0 * 81 + i * 9;

    const bool vA  = (cidx > 0);
    const bool vC  = (cidx < 31);
    const int ofsA = vA ? (w0 - 4) : 0;
    const int ofsC = vC ? (w0 + 4) : 120;

    // depth-1 prefetch, branchless
    float4 nx = *(const float4*)(p1);
    float4 nA = *(const float4*)(p2 + ofsA);
    float4 nB = *(const float4*)(p2 + w0);
    float4 nC = *(const float4*)(p2 + ofsC);

    for (int c = 0; c < 128; ++c) {
      const float4 xv = nx, fA = nA, fB = nB, fC = nC;
      const int adv = (c < 127) ? 8192 : 0;     // cndmask, no branch
      p1 += adv;
      p2 += adv;
      nx = *(const float4*)(p1);
      nA = *(const float4*)(p2 + ofsA);
      nB = *(const float4*)(p2 + w0);
      nC = *(const float4*)(p2 + ofsC);

      alignas(16) float f2r[12];
      f2r[0] = vA ? fA.x : 0.f;
      f2r[1] = vA ? fA.y : 0.f;
      f2r[2] = vA ? fA.z : 0.f;
      f2r[3] = vA ? fA.w : 0.f;
      f2r[4] = fB.x; f2r[5] = fB.y; f2r[6] = fB.z; f2r[7] = fB.w;
      f2r[8]  = vC ? fC.x : 0.f;
      f2r[9]  = vC ? fC.y : 0.f;
      f2r[10] = vC ? fC.z : 0.f;
      f2r[11] = vC ? fC.w : 0.f;

      alignas(16) const float xx[4] = {xv.x, xv.y, xv.z, xv.w};

      const float* avp = Ab + (size_t)c * 81;   // wave-uniform -> s_load
#pragma unroll
      for (int j = 0; j < 9; ++j) {
        const float wj = avp[j];
#pragma unroll
        for (int k = 0; k < 4; ++k) acc[j][k] += wj * (xx[k] * f2r[k + j]);
      }
    }
  }

  float* dst = half ? part : out;
  const float inv = 1.0f / 256.0f;
#pragma unroll
  for (int j = 0; j < 9; ++j) {
    float4 o;
    o.x = acc[j][0] * inv;
    o.y = acc[j][1] * inv;
    o.z = acc[j][2] * inv;
    o.w = acc[j][3] * inv;
    *(float4*)(dst + (((size_t)(b * 81 + i * 9 + j) * 64 + h) << 7) + w0) = o;
  }
}

// ---------------------------------------------------------------------------
// Combine: out += channel-half-1 partial. 663,552 float4s, grid 2592 x 256.
// ---------------------------------------------------------------------------
__global__ __launch_bounds__(256) void combine_kernel(
    float* __restrict__ out, const float* __restrict__ part) {
  const size_t idx = (size_t)blockIdx.x * 256 + threadIdx.x;  // float4 index
  float4* o4       = (float4*)out;
  const float4* p4 = (const float4*)part;
  const float4 a = o4[idx], p = p4[idx];
  float4 rv;
  rv.x = a.x + p.x; rv.y = a.y + p.y; rv.z = a.z + p.z; rv.w = a.w + p.w;
  o4[idx] = rv;
}

// ---------------------------------------------------------------------------
extern "C" void kernel_launch(void* const* d_in, const int* in_sizes, int n_in,
                              void* d_out, int out_size, void* d_ws, size_t ws_size,
                              hipStream_t stream) {
  const float* feat1 = (const float*)d_in[0];
  const float* feat2 = (const float*)d_in[1];
  const float* w1    = (const float*)d_in[2];
  const float* b1    = (const float*)d_in[3];
  const float* w2    = (const float*)d_in[4];
  const float* b2    = (const float*)d_in[5];
  float* out = (float*)d_out;

  float* pooled = (float*)d_ws;                 // 82,944 floats
  float* At     = pooled + 82944;               // 82,944 floats
  float* cpart  = At + 82944;                   // 2,654,208 floats

  corr_pool_kernel<<<1024, 576, 0, stream>>>(feat1, feat2, pooled);
  mlp_kernel<<<4 * 81, 256, 0, stream>>>(pooled, w1, b1, w2, b2, At);
  out_kernel<<<2304, 64, 0, stream>>>(feat1, feat2, At, out, cpart);
  combine_kernel<<<2592, 256, 0, stream>>>(out, cpart);
}